// Round 9
// baseline (1769.069 us; speedup 1.0000x reference)
//
#include <hip/hip_runtime.h>
#include <hip/hip_bf16.h>
#include <math.h>
#include <stdint.h>

typedef __hip_bfloat16 bf16;
typedef __attribute__((ext_vector_type(8))) short short8;
typedef __attribute__((ext_vector_type(4))) short short4v;
typedef __attribute__((ext_vector_type(4))) float f32x4;

#define CC 66
#define TT 100
#define JJ 22
#define HH 8
#define HD 64
#define EE 512
#define CPAD 101

#define SPT_R 112
#define SPT_S 96
#define TP_R 80
#define TP_S 128

#define W_STWK 0
#define W_STWV 65536
#define W_STWQ 131072
#define W_STWO 180224
#define W_TSWK 221184
#define W_TSWV 270336
#define W_TSWQ 319488
#define W_TSWO 385024
#define W_TOTAL 442368

__device__ __forceinline__ float b2f(bf16 v){ return __bfloat162float(v); }
__device__ __forceinline__ bf16 f2b(float v){ return __float2bfloat16(v); }
__device__ __forceinline__ short sb(float v){ __hip_bfloat16 h = __float2bfloat16(v); return *(short*)&h; }
__device__ __forceinline__ float fb(short s){ __hip_bfloat16 h; *(short*)&h = s; return __bfloat162float(h); }

// ---------------------------------------------------------------- k_trall
// all 8 weight transposes in one launch: gridDim.y = section id
__global__ void k_trall(
    const float* __restrict__ st_wk, const float* __restrict__ st_wv,
    const float* __restrict__ st_wq, const float* __restrict__ st_wo,
    const float* __restrict__ ts_wk, const float* __restrict__ ts_wv,
    const float* __restrict__ ts_wq, const float* __restrict__ ts_wo,
    bf16* __restrict__ wsec)
{
  const float* src; bf16* dst; int Rsrc, Csrc, JP, IP;
  switch (blockIdx.y) {
    case 0: src=st_wk; dst=wsec+W_STWK; Rsrc=TT; Csrc=EE; JP=EE; IP=128; break;
    case 1: src=st_wv; dst=wsec+W_STWV; Rsrc=TT; Csrc=EE; JP=EE; IP=128; break;
    case 2: src=st_wq; dst=wsec+W_STWQ; Rsrc=CC; Csrc=EE; JP=EE; IP=96;  break;
    case 3: src=st_wo; dst=wsec+W_STWO; Rsrc=EE; Csrc=CC; JP=80; IP=512; break;
    case 4: src=ts_wk; dst=wsec+W_TSWK; Rsrc=CC; Csrc=EE; JP=EE; IP=96;  break;
    case 5: src=ts_wv; dst=wsec+W_TSWV; Rsrc=CC; Csrc=EE; JP=EE; IP=96;  break;
    case 6: src=ts_wq; dst=wsec+W_TSWQ; Rsrc=TT; Csrc=EE; JP=EE; IP=128; break;
    default:src=ts_wo; dst=wsec+W_TSWO; Rsrc=EE; Csrc=TT; JP=112;IP=512; break;
  }
  int o = blockIdx.x*256 + threadIdx.x;
  if (o >= JP*IP) return;
  int j = o / IP, i = o - j*IP;
  float v = (j < Csrc && i < Rsrc) ? src[(long)i*Csrc + j] : 0.f;
  dst[o] = f2b(v);
}

// ---------------------------------------------------------------- k_prep
__global__ __launch_bounds__(256) void k_prep(
    const float* __restrict__ x, const float* __restrict__ adj,
    const float* __restrict__ sadj, const float* __restrict__ tmask,
    const float* __restrict__ tadj,
    bf16* __restrict__ spT_all, bf16* __restrict__ tp_all)
{
  __shared__ float s_x[CC*TT];
  __shared__ float s_Mt[TT*TT];
  __shared__ float s_A[JJ*JJ];
  __shared__ float s_dis[JJ];
  const int b = blockIdx.x, tid = threadIdx.x;
  const long bb = (long)b * (CC*TT);

  if (tid < JJ) {
    float dsum = 0.f;
    for (int i = 0; i < JJ; ++i) dsum += adj[tid*JJ + i];
    s_dis[tid] = dsum > 0.f ? rsqrtf(dsum) : 0.f;
  }
  for (int o = tid; o < CC*TT; o += 256) s_x[o] = x[bb + o];
  for (int o = tid; o < TT*TT; o += 256) {
    int f = o / TT, t = o - f*TT;
    s_Mt[t*TT + f] = tadj[o] * tmask[o];
  }
  __syncthreads();
  for (int o = tid; o < JJ*JJ; o += 256) {
    int v = o / JJ, j = o - v*JJ;
    s_A[o] = sadj[o] * adj[o] * s_dis[v] * s_dis[j];
  }
  __syncthreads();

  bf16* spT = spT_all + (long)b * (SPT_R*SPT_S);
  bf16* tp  = tp_all  + (long)b * (TP_R*TP_S);

  for (int o = tid; o < SPT_R*SPT_S; o += 256) {
    int t = o / SPT_S, c = o - t*SPT_S;
    float acc = 0.f;
    if (t < TT && c < CC) {
      int v = c / 3, dd = c - v*3;
      for (int j = 0; j < JJ; ++j) acc += s_A[v*JJ + j] * s_x[(j*3 + dd)*TT + t];
    }
    spT[o] = f2b(acc);
  }
  for (int o = tid; o < TP_R*TP_S; o += 256) {
    int n = o / TP_S, f = o - n*TP_S;
    float acc = 0.f;
    if (n < CC && f < TT) {
      float a0 = 0.f, a1 = 0.f;
      for (int t = 0; t < TT; t += 2) {
        a0 += s_x[n*TT + t    ] * s_Mt[(t    )*TT + f];
        a1 += s_x[n*TT + t + 1] * s_Mt[(t + 1)*TT + f];
      }
      acc = a0 + a1;
    }
    tp[o] = f2b(acc);
  }
}

// ---------------------------------------------------------------- MFMA helper
// A[m=lane&15][k=quad*8+j]; B[n=lane&15][k=quad*8+j]; D col=lane&15,row=quad*4+reg
template<int Mt, int Nt, int kch>
__device__ __forceinline__ void mm_tiles(
    const short* __restrict__ A, int sA,
    const short* __restrict__ Bm, int sB,
    short* __restrict__ D, int sD,
    const float* __restrict__ bias, float scale,
    int wave, int ln, int qd)
{
  for (int ti = wave; ti < Mt*Nt; ti += 8) {
    int mi = ti / Nt, ni = ti - mi*Nt;
    f32x4 acc = {0.f, 0.f, 0.f, 0.f};
    const short* ap = A  + (long)(mi*16 + ln)*sA + qd*8;
    const short* bp = Bm + (long)(ni*16 + ln)*sB + qd*8;
    #pragma unroll
    for (int kc = 0; kc < kch; ++kc) {
      short8 af = *(const short8*)(ap + kc*32);
      short8 bf = *(const short8*)(bp + kc*32);
      acc = __builtin_amdgcn_mfma_f32_16x16x32_bf16(af, bf, acc, 0, 0, 0);
    }
    int col = ni*16 + ln;
    float bv_ = bias ? bias[col] : 0.f;
    short* dp = D + (mi*16 + qd*4)*sD + col;
    #pragma unroll
    for (int r = 0; r < 4; ++r) dp[r*sD] = sb((acc[r] + bv_) * scale);
  }
}

// ---------------------------------------------------------------- k_attn (MFMA)
// Templated on direction: all tile counts / strides / k-depths constexpr so the
// compiler unrolls and pipelines the global fragment loads. grid = B blocks.
template<int a>
__global__ __launch_bounds__(512, 4) void k_attn_t(
    const bf16* __restrict__ spT_all, const bf16* __restrict__ tp_all,
    const bf16* __restrict__ wsec,
    const float* __restrict__ bq_g, const float* __restrict__ bv_g,
    float* __restrict__ comb_g)
{
  constexpr int qrows = a ? CC : TT;
  constexpr int krows = a ? TT : CC;
  constexpr int Mq  = a ? 5 : 7;
  constexpr int Mk  = a ? 7 : 5;
  constexpr int qch = a ? 4 : 3;
  constexpr int kch = a ? 3 : 4;
  constexpr int pch = a ? 4 : 3;
  constexpr int sAq = a ? TP_S  : SPT_S;
  constexpr int sAk = a ? SPT_S : TP_S;
  constexpr int RPW = (qrows + 7) / 8;   // softmax rows per wave

  __shared__ __align__(16) short Km [SPT_R*72];
  __shared__ __align__(16) short VTm[64*136];
  __shared__ __align__(16) short Qm [SPT_R*72];
  __shared__ __align__(16) short Pm [SPT_R*136];
  __shared__ float bqL[EE], bvL[EE];

  const int b = blockIdx.x, tid = threadIdx.x;
  const long bb = (long)b * (CC*TT);
  const int wave = tid >> 6, lane = tid & 63, ln = lane & 15, qd = lane >> 4;

  const short* Aq = (const short*)(a ? tp_all  + (long)b*TP_R*TP_S
                                     : spT_all + (long)b*SPT_R*SPT_S);
  const short* Ak = (const short*)(a ? spT_all + (long)b*SPT_R*SPT_S
                                     : tp_all  + (long)b*TP_R*TP_S);
  const short* wqT = (const short*)(wsec + (a ? W_TSWQ : W_STWQ));
  const short* wkT = (const short*)(wsec + (a ? W_TSWK : W_STWK));
  const short* wvT = (const short*)(wsec + (a ? W_TSWV : W_STWV));
  const short* woT = (const short*)(wsec + (a ? W_TSWO : W_STWO));

  // biases -> LDS once; zero P/VT pads
  bqL[tid] = bq_g[tid];
  bvL[tid] = bv_g[tid];
  for (int o = tid; o < SPT_R*136; o += 512) Pm[o] = 0;
  for (int o = tid; o < 64*136;   o += 512) VTm[o] = 0;
  __syncthreads();

  f32x4 accO[5];
  { f32x4 z = {0.f,0.f,0.f,0.f}; for (int i = 0; i < 5; ++i) accO[i] = z; }

  for (int h = 0; h < HH; ++h) {
    const int base = h*HD;
    mm_tiles<Mk, 4, kch>(Ak, sAk, wkT + (long)base*sAk, sAk, Km, 72,
                         nullptr, 1.f, wave, ln, qd);            // K
    mm_tiles<4, Mk, kch>(wvT + (long)base*sAk, sAk, Ak, sAk, VTm, 136,
                         nullptr, 1.f, wave, ln, qd);            // V^T
    mm_tiles<Mq, 4, qch>(Aq, sAq, wqT + (long)base*sAq, sAq, Qm, 72,
                         bqL + base, 1.f, wave, ln, qd);         // Q (+bq)
    __syncthreads();
    mm_tiles<Mq, Mk, 2>(Qm, 72, Km, 72, Pm, 136, nullptr, 0.125f, wave, ln, qd);
    __syncthreads();
    // softmax: consecutive lanes -> consecutive rows, all 8 waves engaged
    {
      int r = wave*RPW + lane;
      if (lane < RPW && r < qrows) {
        short* pr = Pm + r*136;
        constexpr int full = krows >> 2, rem = krows & 3;
        float mx = -INFINITY;
        #pragma unroll 4
        for (int j4 = 0; j4 < full; ++j4) {
          short4v v = ((const short4v*)pr)[j4];
          mx = fmaxf(mx, fmaxf(fmaxf(fb(v.x), fb(v.y)), fmaxf(fb(v.z), fb(v.w))));
        }
        for (int j = full*4; j < full*4 + rem; ++j) mx = fmaxf(mx, fb(pr[j]));
        float sum = 0.f;
        #pragma unroll 4
        for (int j4 = 0; j4 < full; ++j4) {
          short4v v = ((const short4v*)pr)[j4];
          sum += __expf(fb(v.x)-mx) + __expf(fb(v.y)-mx)
               + __expf(fb(v.z)-mx) + __expf(fb(v.w)-mx);
        }
        for (int j = full*4; j < full*4 + rem; ++j) sum += __expf(fb(pr[j]) - mx);
        float rs = 1.f / sum;
        #pragma unroll 4
        for (int j4 = 0; j4 < full; ++j4) {
          short4v v = ((const short4v*)pr)[j4];
          short4v w;
          w.x = sb(__expf(fb(v.x)-mx)*rs); w.y = sb(__expf(fb(v.y)-mx)*rs);
          w.z = sb(__expf(fb(v.z)-mx)*rs); w.w = sb(__expf(fb(v.w)-mx)*rs);
          ((short4v*)pr)[j4] = w;
        }
        for (int j = full*4; j < full*4 + rem; ++j)
          pr[j] = sb(__expf(fb(pr[j]) - mx)*rs);
      }
    }
    __syncthreads();
    mm_tiles<Mq, 4, pch>(Pm, 136, VTm, 136, Qm, 72, bvL + base, 1.f,
                         wave, ln, qd);                          // O = P@V + bv
    __syncthreads();
    // out += O @ wo
    {
      int idx = 0;
      for (int ti = wave; ti < Mq*Mk; ti += 8, ++idx) {
        int mi = ti / Mk, ni = ti - mi*Mk;
        const short* ap = Qm + (mi*16 + ln)*72 + qd*8;
        const short* bp = woT + (long)(ni*16 + ln)*512 + base + qd*8;
        f32x4 acc = accO[idx];
        acc = __builtin_amdgcn_mfma_f32_16x16x32_bf16(*(const short8*)ap,
                                                      *(const short8*)bp, acc, 0,0,0);
        acc = __builtin_amdgcn_mfma_f32_16x16x32_bf16(*(const short8*)(ap+32),
                                                      *(const short8*)(bp+32), acc, 0,0,0);
        accO[idx] = acc;
      }
    }
    __syncthreads();
  }

  {
    int idx = 0;
    for (int ti = wave; ti < Mq*Mk; ti += 8, ++idx) {
      int mi = ti / Mk, ni = ti - mi*Mk;
      int col = ni*16 + ln;
      #pragma unroll
      for (int r = 0; r < 4; ++r) {
        int row = mi*16 + qd*4 + r;
        if (row < qrows && col < krows) {
          long off = a ? ((long)row*TT + col) : ((long)col*TT + row);
          atomicAdd(&comb_g[bb + off], accO[idx][r]);
        }
      }
    }
  }
}

// ---------------------------------------------------------------- k_epi
__global__ __launch_bounds__(256) void k_epi(
    const float* __restrict__ comb_g, const float* __restrict__ x,
    const float* __restrict__ st_bo, const float* __restrict__ ts_bo,
    const float* __restrict__ alpha, const float* __restrict__ beta,
    const float* __restrict__ fcw, const float* __restrict__ fcb,
    float* __restrict__ out)
{
  __shared__ float s_cb[CC*CPAD];
  __shared__ float s_w[TT*TT];
  const int b = blockIdx.x, tid = threadIdx.x;
  const long bb = (long)b * (CC*TT);

  for (int o = tid; o < CC*TT; o += 256) {
    int c = o / TT, t = o - c*TT;
    s_cb[c*CPAD + t] = comb_g[bb + o] + st_bo[c] + ts_bo[t];
  }
  for (int o = tid; o < TT*TT; o += 256) {
    int f = o / TT, t = o - f*TT;
    s_w[t*TT + f] = fcw[o];
  }
  __syncthreads();
  if (tid < TT) {
    const int t = tid;
    float mean = 0.f;
    for (int c = 0; c < CC; ++c) mean += s_cb[c*CPAD + t];
    mean *= (1.f/CC);
    float var = 0.f;
    for (int c = 0; c < CC; ++c) { float dv = s_cb[c*CPAD + t] - mean; var += dv*dv; }
    var *= (1.f/CC);
    float rstd = 1.f / sqrtf(var + 1e-5f);
    for (int c = 0; c < CC; ++c) {
      float y = (s_cb[c*CPAD + t] - mean) * rstd * alpha[c] + beta[c];
      s_cb[c*CPAD + t] = y + x[bb + c*TT + t];
    }
  }
  __syncthreads();
  for (int o = tid; o < CC*TT; o += 256) {
    int c = o / TT, f = o - c*TT;
    const float* cr = s_cb + c*CPAD;
    float a0 = 0.f, a1 = 0.f;
    for (int t = 0; t < TT; t += 2) {
      a0 += cr[t    ] * s_w[(t    )*TT + f];
      a1 += cr[t + 1] * s_w[(t + 1)*TT + f];
    }
    out[bb + o] = tanhf(a0 + a1 + fcb[f]);
  }
}

// ---------------------------------------------------------------- R4 fallback
__global__ __launch_bounds__(128) void k_fused(
    const float* __restrict__ x, const float* __restrict__ adj,
    const float* __restrict__ sadj, const float* __restrict__ tmask,
    const float* __restrict__ tadj,
    const float* __restrict__ st_wq, const float* __restrict__ st_bq,
    const float* __restrict__ st_wk, const float* __restrict__ st_bk,
    const float* __restrict__ st_wv, const float* __restrict__ st_bv,
    const float* __restrict__ st_wo, const float* __restrict__ st_bo,
    const float* __restrict__ ts_wq, const float* __restrict__ ts_bq,
    const float* __restrict__ ts_wk, const float* __restrict__ ts_bk,
    const float* __restrict__ ts_wv, const float* __restrict__ ts_bv,
    const float* __restrict__ ts_wo, const float* __restrict__ ts_bo,
    const float* __restrict__ alpha, const float* __restrict__ beta,
    const float* __restrict__ fcw, const float* __restrict__ fcb,
    float* __restrict__ out)
{
  __shared__ float s_sp[CC*TT];
  __shared__ float s_tp[CC*TT];
  __shared__ __align__(16) float s_kv[2*TT*HD];
  __shared__ float s_comb[CC*CPAD];
  __shared__ float s_A[JJ*JJ];
  __shared__ float s_dis[JJ];

  const int b = blockIdx.x, tid = threadIdx.x;
  const long bb = (long)b * (CC*TT);
  float* s_xs = s_comb;
  float* s_Mt = s_kv;

  if (tid < JJ) {
    float dsum = 0.f;
    for (int i = 0; i < JJ; ++i) dsum += adj[tid*JJ + i];
    s_dis[tid] = dsum > 0.f ? rsqrtf(dsum) : 0.f;
  }
  for (int o = tid; o < CC*TT; o += 128) s_xs[o] = x[bb + o];
  for (int o = tid; o < TT*TT; o += 128) {
    int f = o / TT, t = o - f*TT;
    s_Mt[t*TT + f] = tadj[o] * tmask[o];
  }
  __syncthreads();
  for (int o = tid; o < JJ*JJ; o += 128) {
    int v = o / JJ, j = o - v*JJ;
    s_A[o] = sadj[o] * adj[o] * s_dis[v] * s_dis[j];
  }
  __syncthreads();

  for (int o = tid; o < CC*TT; o += 128) {
    int c = o / TT, t = o - c*TT, v = c / 3, dd = c - v*3;
    float acc = 0.f;
    for (int j = 0; j < JJ; ++j) acc += s_A[v*JJ + j] * s_xs[(j*3 + dd)*TT + t];
    s_sp[o] = acc;
  }
  for (int o = tid; o < CC*TT; o += 128) {
    int n = o / TT, f = o - n*TT;
    float a0 = 0.f, a1 = 0.f;
    for (int t = 0; t < TT; t += 2) {
      a0 += s_xs[n*TT + t    ] * s_Mt[(t    )*TT + f];
      a1 += s_xs[n*TT + t + 1] * s_Mt[(t + 1)*TT + f];
    }
    s_tp[o] = a0 + a1;
  }
  __syncthreads();

  for (int o = tid; o < CC*TT; o += 128) {
    int c = o / TT, t = o - c*TT;
    s_comb[c*CPAD + t] = st_bo[c] + ts_bo[t];
  }

  {
    float* s_k = s_kv;
    float* s_v = s_kv + TT*HD;
    for (int h = 0; h < HH; ++h) {
      const int base = h*HD;
      __syncthreads();
      {
        const int d = tid & 63, krow = tid >> 6;
        for (int kk = 0; kk < CC/2; ++kk) {
          int k = kk*2 + krow;
          float aK = st_bk[base + d], aV = st_bv[base + d];
          const float* tr = s_tp + k*TT;
          for (int t = 0; t < TT; ++t) {
            float a = tr[t];
            aK += a * st_wk[(long)t*EE + base + d];
            aV += a * st_wv[(long)t*EE + base + d];
          }
          s_k[k*HD + d] = aK;
          s_v[k*HD + d] = aV;
        }
      }
      __syncthreads();
      if (tid < TT) {
        const int q = tid;
        float qv[HD];
        #pragma unroll
        for (int d = 0; d < HD; ++d) qv[d] = st_bq[base + d];
        for (int c = 0; c < CC; ++c) {
          float a = s_sp[c*TT + q];
          const float* wr = st_wq + (long)c*EE + base;
          #pragma unroll
          for (int d = 0; d < HD; ++d) qv[d] += a * wr[d];
        }
        float m = -INFINITY, l = 0.f, ov[HD];
        #pragma unroll
        for (int d = 0; d < HD; ++d) ov[d] = 0.f;
        for (int k = 0; k < CC; ++k) {
          const float4* kr4 = (const float4*)(s_k + k*HD);
          float s0=0.f,s1=0.f,s2=0.f,s3=0.f;
          #pragma unroll
          for (int i = 0; i < 16; ++i) {
            float4 kk4 = kr4[i];
            s0 += qv[4*i  ]*kk4.x; s1 += qv[4*i+1]*kk4.y;
            s2 += qv[4*i+2]*kk4.z; s3 += qv[4*i+3]*kk4.w;
          }
          float s  = (s0+s1+s2+s3) * 0.125f;
          float mn = fmaxf(m, s);
          float corr = __expf(m - mn);
          float p    = __expf(s - mn);
          l = l*corr + p;
          const float4* vr4 = (const float4*)(s_v + k*HD);
          #pragma unroll
          for (int i = 0; i < 16; ++i) {
            float4 vv4 = vr4[i];
            ov[4*i  ] = ov[4*i  ]*corr + p*vv4.x;
            ov[4*i+1] = ov[4*i+1]*corr + p*vv4.y;
            ov[4*i+2] = ov[4*i+2]*corr + p*vv4.z;
            ov[4*i+3] = ov[4*i+3]*corr + p*vv4.w;
          }
          m = mn;
        }
        float rl = 1.f/l;
        #pragma unroll
        for (int d = 0; d < HD; ++d) ov[d] *= rl;
        for (int c = 0; c < CC; ++c) {
          const float* wr = st_wo + (long)base*CC + c;
          float a0=0.f,a1=0.f,a2=0.f,a3=0.f;
          #pragma unroll
          for (int d = 0; d < HD; d += 4) {
            a0 += ov[d  ]*wr[(long)(d  )*CC]; a1 += ov[d+1]*wr[(long)(d+1)*CC];
            a2 += ov[d+2]*wr[(long)(d+2)*CC]; a3 += ov[d+3]*wr[(long)(d+3)*CC];
          }
          s_comb[c*CPAD + q] += a0+a1+a2+a3;
        }
      }
    }
  }

  {
    float* s_k = s_kv;
    float* s_v = s_kv + TT*HD;
    for (int h = 0; h < HH; ++h) {
      const int base = h*HD;
      __syncthreads();
      {
        const int d = tid & 63, krow = tid >> 6;
        for (int kk = 0; kk < TT/2; ++kk) {
          int k = kk*2 + krow;
          float aK = ts_bk[base + d], aV = ts_bv[base + d];
          for (int c = 0; c < CC; ++c) {
            float a = s_sp[c*TT + k];
            aK += a * ts_wk[(long)c*EE + base + d];
            aV += a * ts_wv[(long)c*EE + base + d];
          }
          s_k[k*HD + d] = aK;
          s_v[k*HD + d] = aV;
        }
      }
      __syncthreads();
      if (tid < CC) {
        const int q = tid;
        float qv[HD];
        #pragma unroll
        for (int d = 0; d < HD; ++d) qv[d] = ts_bq[base + d];
        const float* tr = s_tp + q*TT;
        for (int t = 0; t < TT; ++t) {
          float a = tr[t];
          const float* wr = ts_wq + (long)t*EE + base;
          #pragma unroll
          for (int d = 0; d < HD; ++d) qv[d] += a * wr[d];
        }
        float m = -INFINITY, l = 0.f, ov[HD];
        #pragma unroll
        for (int d = 0; d < HD; ++d) ov[d] = 0.f;
        for (int k = 0; k < TT; ++k) {
          const float4* kr4 = (const float4*)(s_k + k*HD);
          float s0=0.f,s1=0.f,s2=0.f,s3=0.f;
          #pragma unroll
          for (int i = 0; i < 16; ++i) {
            float4 kk4 = kr4[i];
            s0 += qv[4*i  ]*kk4.x; s1 += qv[4*i+1]*kk4.y;
            s2 += qv[4*i+2]*kk4.z; s3 += qv[4*i+3]*kk4.w;
          }
          float s  = (s0+s1+s2+s3) * 0.125f;
          float mn = fmaxf(m, s);
          float corr = __expf(m - mn);
          float p    = __expf(s - mn);
          l = l*corr + p;
          const float4* vr4 = (const float4*)(s_v + k*HD);
          #pragma unroll
          for (int i = 0; i < 16; ++i) {
            float4 vv4 = vr4[i];
            ov[4*i  ] = ov[4*i  ]*corr + p*vv4.x;
            ov[4*i+1] = ov[4*i+1]*corr + p*vv4.y;
            ov[4*i+2] = ov[4*i+2]*corr + p*vv4.z;
            ov[4*i+3] = ov[4*i+3]*corr + p*vv4.w;
          }
          m = mn;
        }
        float rl = 1.f/l;
        #pragma unroll
        for (int d = 0; d < HD; ++d) ov[d] *= rl;
        for (int t = 0; t < TT; ++t) {
          const float* wr = ts_wo + (long)base*TT + t;
          float a0=0.f,a1=0.f,a2=0.f,a3=0.f;
          #pragma unroll
          for (int d = 0; d < HD; d += 4) {
            a0 += ov[d  ]*wr[(long)(d  )*TT]; a1 += ov[d+1]*wr[(long)(d+1)*TT];
            a2 += ov[d+2]*wr[(long)(d+2)*TT]; a3 += ov[d+3]*wr[(long)(d+3)*TT];
          }
          s_comb[q*CPAD + t] += a0+a1+a2+a3;
        }
      }
    }
  }
  __syncthreads();

  if (tid < TT) {
    const int t = tid;
    float mean = 0.f;
    for (int c = 0; c < CC; ++c) mean += s_comb[c*CPAD + t];
    mean *= (1.f/CC);
    float var = 0.f;
    for (int c = 0; c < CC; ++c) { float dv = s_comb[c*CPAD + t] - mean; var += dv*dv; }
    var *= (1.f/CC);
    float rstd = 1.f / sqrtf(var + 1e-5f);
    for (int c = 0; c < CC; ++c) {
      float y = (s_comb[c*CPAD + t] - mean) * rstd * alpha[c] + beta[c];
      s_comb[c*CPAD + t] = y + x[bb + c*TT + t];
    }
  }
  __syncthreads();

  float* s_w = s_kv;
  for (int o = tid; o < TT*TT; o += 128) {
    int f = o / TT, t = o - f*TT;
    s_w[t*TT + f] = fcw[o];
  }
  __syncthreads();

  for (int o = tid; o < CC*TT; o += 128) {
    int c = o / TT, f = o - c*TT;
    const float* cr = s_comb + c*CPAD;
    float a0 = 0.f, a1 = 0.f;
    for (int t = 0; t < TT; t += 2) {
      a0 += cr[t    ] * s_w[(t    )*TT + f];
      a1 += cr[t + 1] * s_w[(t + 1)*TT + f];
    }
    out[bb + o] = tanhf(a0 + a1 + fcb[f]);
  }
}

// ---------------------------------------------------------------- launch
extern "C" void kernel_launch(void* const* d_in, const int* in_sizes, int n_in,
                              void* d_out, int out_size, void* d_ws, size_t ws_size,
                              hipStream_t stream) {
  const float* x     = (const float*)d_in[0];
  const float* adj   = (const float*)d_in[1];
  const float* sadj  = (const float*)d_in[2];
  const float* tmask = (const float*)d_in[3];
  const float* tadj  = (const float*)d_in[4];
  const float* st_wq = (const float*)d_in[5];  const float* st_bq = (const float*)d_in[6];
  const float* st_wk = (const float*)d_in[7];  const float* st_bk = (const float*)d_in[8];
  const float* st_wv = (const float*)d_in[9];  const float* st_bv = (const float*)d_in[10];
  const float* st_wo = (const float*)d_in[11]; const float* st_bo = (const float*)d_in[12];
  const float* ts_wq = (const float*)d_in[13]; const float* ts_bq = (const float*)d_in[14];
  const float* ts_wk = (const float*)d_in[15]; const float* ts_bk = (const float*)d_in[16];
  const float* ts_wv = (const float*)d_in[17]; const float* ts_bv = (const float*)d_in[18];
  const float* ts_wo = (const float*)d_in[19]; const float* ts_bo = (const float*)d_in[20];
  const float* alpha = (const float*)d_in[21]; const float* beta  = (const float*)d_in[22];
  const float* fcw   = (const float*)d_in[23]; const float* fcb   = (const float*)d_in[24];
  float* out = (float*)d_out;

  const int B = in_sizes[0] / (CC*TT);
  const size_t comb_bytes = (size_t)B * CC * TT * 4;
  const size_t w_bytes    = (size_t)W_TOTAL * 2;
  const size_t spt_bytes  = (size_t)B * SPT_R * SPT_S * 2;
  const size_t tp_bytes   = (size_t)B * TP_R * TP_S * 2;
  const size_t need = comb_bytes + w_bytes + spt_bytes + tp_bytes;

  if (ws_size >= need) {
    float* comb_g  = (float*)d_ws;
    bf16*  wsec    = (bf16*)((char*)d_ws + comb_bytes);
    bf16*  spT_all = (bf16*)((char*)d_ws + comb_bytes + w_bytes);
    bf16*  tp_all  = spT_all + (size_t)B * SPT_R * SPT_S;

    hipMemsetAsync(comb_g, 0, comb_bytes, stream);
    dim3 trg((EE*512 + 255)/256, 8);
    k_trall<<<trg, 256, 0, stream>>>(st_wk, st_wv, st_wq, st_wo,
                                     ts_wk, ts_wv, ts_wq, ts_wo, wsec);
    k_prep<<<B, 256, 0, stream>>>(x, adj, sadj, tmask, tadj, spT_all, tp_all);
    k_attn_t<0><<<B, 512, 0, stream>>>(spT_all, tp_all, wsec, st_bq, st_bv, comb_g);
    k_attn_t<1><<<B, 512, 0, stream>>>(spT_all, tp_all, wsec, ts_bq, ts_bv, comb_g);
    k_epi<<<B, 256, 0, stream>>>(comb_g, x, st_bo, ts_bo, alpha, beta, fcw, fcb, out);
  } else {
    k_fused<<<B, 128, 0, stream>>>(x, adj, sadj, tmask, tadj,
                                   st_wq, st_bq, st_wk, st_bk, st_wv, st_bv, st_wo, st_bo,
                                   ts_wq, ts_bq, ts_wk, ts_bk, ts_wv, ts_bv, ts_wo, ts_bo,
                                   alpha, beta, fcw, fcb, out);
  }
}